// Round 1
// 257.018 us; speedup vs baseline: 1.0415x; 1.0415x over previous
//
#include <hip/hip_runtime.h>

typedef unsigned short u16;
typedef short s16x8 __attribute__((ext_vector_type(8)));
typedef float f32x4 __attribute__((ext_vector_type(4)));
typedef unsigned short u16x8 __attribute__((ext_vector_type(8)));

#define B_   8
#define N_   24000
#define M_   6000
#define K_   32
#define CIN  64
#define CMID 128
#define COUT 256
#define KP1  96    // 67 zero-padded to 3x32 for MFMA K-steps
#define QB_  188   // ceil(M/32) query-blocks per (batch, quarter) combo

// Static device globals — no ws_size assumption, graph-capture safe,
// fully rewritten on every call. Weights in MFMA fragment order.
__device__ __align__(16) u16 g_W1f[CMID * KP1];                 // 24.6 KB bf16
__device__ __align__(16) u16 g_W2f[COUT * CMID];                // 65.5 KB bf16
__device__ __align__(16) u16 g_Yf[(size_t)B_ * N_ * COUT];      // 98.3 MB bf16

__device__ __forceinline__ float bf2f(u16 u) {
    return __uint_as_float(((unsigned)u) << 16);
}
__device__ __forceinline__ u16 f2bf(float f) {  // fp32 -> bf16 RNE
    unsigned u = __float_as_uint(f);
    u += 0x7FFFu + ((u >> 16) & 1u);
    return (u16)(u >> 16);
}

// ---------------------------------------------------------------------------
// Kernel 0: convert fp32 weights to bf16 in fragment order. (unchanged)
// ---------------------------------------------------------------------------
__global__ void prep_weights(const float* __restrict__ W1,
                             const float* __restrict__ W2) {
    int t = blockIdx.x * 256 + threadIdx.x;   // 0..45055
    if (t < CMID * KP1) {                     // 12288 -> W1f
        int blk = t >> 9, off = t & 511;
        int L = off >> 3, j = off & 7;
        int ln = L & 15, quad = L >> 4;
        int w = blk / 6, r = blk % 6;
        int k0i = r >> 1, mt = r & 1;
        int row = w * 32 + mt * 16 + ln;
        int col = k0i * 32 + quad * 8 + j;
        g_W1f[t] = (col < 67) ? f2bf(W1[row * 67 + col]) : (u16)0;
    } else {                                  // 32768 -> W2f
        int i = t - CMID * KP1;
        int blk = i >> 9, off = i & 511;
        int L = off >> 3, j = off & 7;
        int ln = L & 15, quad = L >> 4;
        int w = blk >> 4, r = blk & 15;
        int k0i = r >> 2, mt = r & 3;
        int row = w * 64 + mt * 16 + ln;
        int col = k0i * 32 + quad * 8 + j;
        g_W2f[i] = f2bf(W2[row * 128 + col]);
    }
}

// ---------------------------------------------------------------------------
// Kernel 1: fused conv1+relu+conv2+relu (BYTE-IDENTICAL to R7 — once gather
// drops below it, its counters surface in the top-5 for a theory-led edit).
// ---------------------------------------------------------------------------
__global__ __launch_bounds__(256) void conv_fused(
        const float* __restrict__ feat, const float* __restrict__ xyz,
        const float* __restrict__ b1,  const float* __restrict__ b2) {
    __shared__ __align__(16) u16 sm[16896];
    u16* Xs = sm;
    u16* Hs = sm + 6656;
    u16* Ys = sm;

    const int tid  = threadIdx.x;
    const int b    = blockIdx.y;
    const int n0   = blockIdx.x * 64;
    const int w    = tid >> 6;
    const int L    = tid & 63;
    const int ln   = L & 15;
    const int quad = L >> 4;

    if (tid < 64) {
        uint4 z; z.x = z.y = z.z = z.w = 0u;
        u16* xr = Xs + tid * 104;
        *(uint4*)(xr + 64) = z; *(uint4*)(xr + 72) = z;
        *(uint4*)(xr + 80) = z; *(uint4*)(xr + 88) = z;
        const float* s = xyz + (size_t)(b * N_ + n0 + tid) * 3;
        xr[64] = f2bf(s[0]); xr[65] = f2bf(s[1]); xr[66] = f2bf(s[2]);
    }
#pragma unroll
    for (int it = 0; it < 4; ++it) {
        int idx = it * 256 + tid;
        int c   = idx >> 4;
        int p0  = (idx & 15) << 2;
        float4 v = *(const float4*)(feat + (size_t)(b * CIN + c) * N_ + n0 + p0);
        u16* dst = Xs + p0 * 104 + c;
        dst[0]   = f2bf(v.x);
        dst[104] = f2bf(v.y);
        dst[208] = f2bf(v.z);
        dst[312] = f2bf(v.w);
    }
    __syncthreads();

    f32x4 acc1[2][4];
#pragma unroll
    for (int mt = 0; mt < 2; ++mt)
#pragma unroll
        for (int nt = 0; nt < 4; ++nt) {
            f32x4 zz = {0.f, 0.f, 0.f, 0.f};
            acc1[mt][nt] = zz;
        }
#pragma unroll
    for (int k0i = 0; k0i < 3; ++k0i) {
        s16x8 af[2], xf[4];
#pragma unroll
        for (int mt = 0; mt < 2; ++mt)
            af[mt] = *(const s16x8*)(g_W1f + (((w * 3 + k0i) * 2 + mt) << 9) + L * 8);
#pragma unroll
        for (int nt = 0; nt < 4; ++nt)
            xf[nt] = *(const s16x8*)(Xs + (nt * 16 + ln) * 104 + k0i * 32 + quad * 8);
#pragma unroll
        for (int mt = 0; mt < 2; ++mt)
#pragma unroll
            for (int nt = 0; nt < 4; ++nt)
                acc1[mt][nt] = __builtin_amdgcn_mfma_f32_16x16x32_bf16(
                    af[mt], xf[nt], acc1[mt][nt], 0, 0, 0);
    }
#pragma unroll
    for (int mt = 0; mt < 2; ++mt) {
        int m0 = w * 32 + mt * 16 + quad * 4;
        float4 bv = *(const float4*)(b1 + m0);
#pragma unroll
        for (int nt = 0; nt < 4; ++nt) {
            int p = nt * 16 + ln;
            float x0 = acc1[mt][nt][0] + bv.x;
            float x1 = acc1[mt][nt][1] + bv.y;
            float x2 = acc1[mt][nt][2] + bv.z;
            float x3 = acc1[mt][nt][3] + bv.w;
            ushort4 hv;
            hv.x = f2bf(x0 > 0.f ? x0 : 0.f);
            hv.y = f2bf(x1 > 0.f ? x1 : 0.f);
            hv.z = f2bf(x2 > 0.f ? x2 : 0.f);
            hv.w = f2bf(x3 > 0.f ? x3 : 0.f);
            *(ushort4*)(Hs + p * 136 + m0) = hv;
        }
    }
    __syncthreads();

    f32x4 acc2[4][4];
#pragma unroll
    for (int mt = 0; mt < 4; ++mt)
#pragma unroll
        for (int nt = 0; nt < 4; ++nt) {
            f32x4 zz = {0.f, 0.f, 0.f, 0.f};
            acc2[mt][nt] = zz;
        }
#pragma unroll
    for (int k0i = 0; k0i < 4; ++k0i) {
        s16x8 af[4], hf[4];
#pragma unroll
        for (int mt = 0; mt < 4; ++mt)
            af[mt] = *(const s16x8*)(g_W2f + (((w * 4 + k0i) * 4 + mt) << 9) + L * 8);
#pragma unroll
        for (int nt = 0; nt < 4; ++nt)
            hf[nt] = *(const s16x8*)(Hs + (nt * 16 + ln) * 136 + k0i * 32 + quad * 8);
#pragma unroll
        for (int mt = 0; mt < 4; ++mt)
#pragma unroll
            for (int nt = 0; nt < 4; ++nt)
                acc2[mt][nt] = __builtin_amdgcn_mfma_f32_16x16x32_bf16(
                    af[mt], hf[nt], acc2[mt][nt], 0, 0, 0);
    }
    __syncthreads();

#pragma unroll
    for (int mt = 0; mt < 4; ++mt) {
        int c0 = w * 64 + mt * 16 + quad * 4;
        float4 bv = *(const float4*)(b2 + c0);
#pragma unroll
        for (int nt = 0; nt < 4; ++nt) {
            int p = nt * 16 + ln;
            float x0 = acc2[mt][nt][0] + bv.x;
            float x1 = acc2[mt][nt][1] + bv.y;
            float x2 = acc2[mt][nt][2] + bv.z;
            float x3 = acc2[mt][nt][3] + bv.w;
            ushort4 yv;
            yv.x = f2bf(x0 > 0.f ? x0 : 0.f);
            yv.y = f2bf(x1 > 0.f ? x1 : 0.f);
            yv.z = f2bf(x2 > 0.f ? x2 : 0.f);
            yv.w = f2bf(x3 > 0.f ? x3 : 0.f);
            *(ushort4*)(Ys + p * 264 + c0) = yv;
        }
    }
    __syncthreads();

    u16* dstY = g_Yf + ((size_t)b * N_ + n0) * COUT;
#pragma unroll
    for (int i = 0; i < 8; ++i) {
        int g = i * 256 + tid;
        int p = g >> 5, c16 = g & 31;
        *(uint4*)(dstY + (size_t)p * COUT + c16 * 8) =
            *(const uint4*)(Ys + p * 264 + c16 * 8);
    }
}

// ---------------------------------------------------------------------------
// Kernel 2: gather + max, two-PHASE L2 version.
// R8 counters: FETCH 376 MB vs 98 MB cold-ideal (3.8x re-fetch), MfmaUtil 0,
// VALUBusy 17%, occ 50% -> latency-bound on L2 misses (Yf fits L3, so the
// "46% HBM" is L3-served fill, not a BW wall). Cause: concurrent span =
// 5 blk/CU x 32 CU = 160 blocks vs 188/combo -> the resident window straddles
// a combo boundary ~85% of the time, so two 3.07 MB quarter-slabs (6.1 MB)
// fight over the 4 MB XCD-L2 continuously. Channel-eighths would break the
// 128-B line granularity (the other 64-B half of each line belongs to a
// DIFFERENT XCD's combo), so instead: split the k-loop into two support-point
// PHASES (id<12000, id>=12000) with a persistent register max (zero is exact
// identity for post-ReLU bf16). Half-slab = 1.54 MB; at any instant at most
// two half-slabs (phase drift / combo boundary) = 3.07 MB <= 4 MB -> fits
// ALWAYS. Grid, coalescing (128-B rows), LDS (5 blk/CU cap), output stage all
// byte-identical to R8. Cost: 2x sidx LDS reads + 2x (half exec-masked) load
// issues — noise at 17% VALUBusy. Max in u16 domain = exact bf16 max.
// ---------------------------------------------------------------------------
__global__ __launch_bounds__(256) void gather_max(
        const int* __restrict__ nbr, float* __restrict__ out) {
    __shared__ __align__(16) int sidx[32 * K_];    // 4 KB
    __shared__ __align__(16) u16 ymax[32 * 400];   // 25.6 KB, [m][c] stride 400

    const int tid = threadIdx.x;
    const int l   = blockIdx.x;
    const int xcd = l & 7;
    const int j   = l >> 3;          // 0..751
    const int cw  = j / QB_;         // combo-within-XCD 0..3
    const int qb  = j % QB_;         // query-block 0..187
    const int combo = cw * 8 + xcd;  // 0..31
    const int b   = combo >> 2;
    const int q   = combo & 3;       // channel quarter (64 ch)
    const int m0  = qb * 32;

    // stage neighbor indices: 32 queries x 32 k
    if (m0 + (tid >> 3) < M_)
        *(int4*)(sidx + tid * 4) =
            *(const int4*)(nbr + ((size_t)b * M_ + m0) * K_ + tid * 4);
    __syncthreads();

    const int w  = tid >> 6;         // wave 0..3
    const int L  = tid & 63;
    const int kg = L >> 3;           // k-group 0..7 (neighbor within round)
    const int co = L & 7;            // channel octet within quarter
    const u16* base = g_Yf + (size_t)b * N_ * COUT + q * 64 + co * 8;

    // persistent running max per query (8 queries/wave); 0 = identity (ReLU)
    u16x8 mx[8];
#pragma unroll
    for (int i = 0; i < 8; ++i)
        mx[i] = (u16x8){0, 0, 0, 0, 0, 0, 0, 0};

    // PHASE loop: nh=0 touches support points [0,12000), nh=1 [12000,24000).
    // nh outer (not inner!) so all resident blocks sweep the same half-slab.
#pragma unroll
    for (int nh = 0; nh < 2; ++nh) {
        const unsigned lo = nh ? (unsigned)(N_ / 2) : 0u;
        const unsigned hi = lo + (unsigned)(N_ / 2);
#pragma unroll
        for (int i = 0; i < 8; ++i) {
            int ml = w * 8 + i;
            if (m0 + ml < M_) {
                int id[4];
#pragma unroll
                for (int r = 0; r < 4; ++r)
                    id[r] = sidx[ml * K_ + r * 8 + kg];
                u16x8 v[4];
#pragma unroll
                for (int r = 0; r < 4; ++r) {
                    unsigned u = (unsigned)id[r];
                    u = u < (unsigned)N_ ? u : 0u;   // defensive clamp
                    if (u >= lo && u < hi)           // uniform per 8-lane octet
                        v[r] = *(const u16x8*)(base + (size_t)u * COUT);
                    else
                        v[r] = (u16x8){0, 0, 0, 0, 0, 0, 0, 0};
                }
                u16x8 a = __builtin_elementwise_max(v[0], v[1]);
                u16x8 c = __builtin_elementwise_max(v[2], v[3]);
                mx[i] = __builtin_elementwise_max(
                    mx[i], __builtin_elementwise_max(a, c));
            }
        }
    }

    // reduce across the 8 k-groups (lane bits 3,4,5) after both phases
#pragma unroll
    for (int i = 0; i < 8; ++i) {
        int ml = w * 8 + i;
        if (m0 + ml < M_) {
            u16x8 m8 = mx[i];
#pragma unroll
            for (int mask = 8; mask <= 32; mask <<= 1) {
                int4 t = *(int4*)&m8;
                t.x = __shfl_xor(t.x, mask);
                t.y = __shfl_xor(t.y, mask);
                t.z = __shfl_xor(t.z, mask);
                t.w = __shfl_xor(t.w, mask);
                m8 = __builtin_elementwise_max(m8, *(u16x8*)&t);
            }
            if (kg == 0)   // one replicate writes 8 channels, 16B ds_write
                *(u16x8*)(ymax + ml * 400 + co * 8) = m8;
        }
    }
    __syncthreads();

    // transpose + bf16->fp32: out[b][q*64+c][m0..m0+31]
    int valid = M_ - m0; if (valid > 32) valid = 32;
#pragma unroll
    for (int it = 0; it < 2; ++it) {
        int c  = it * 32 + (tid >> 3);   // local channel 0..63
        int mc = (tid & 7) << 2;
        if (mc + 4 <= valid) {
            float4 v;
            v.x = bf2f(ymax[(mc + 0) * 400 + c]);
            v.y = bf2f(ymax[(mc + 1) * 400 + c]);
            v.z = bf2f(ymax[(mc + 2) * 400 + c]);
            v.w = bf2f(ymax[(mc + 3) * 400 + c]);
            *(float4*)(out + (size_t)(b * COUT + q * 64 + c) * M_ + m0 + mc) = v;
        }
    }
}

extern "C" void kernel_launch(void* const* d_in, const int* in_sizes, int n_in,
                              void* d_out, int out_size, void* d_ws, size_t ws_size,
                              hipStream_t stream) {
    // inputs (all fp32 except neighbor_idx int32):
    // 0=query_xyz(unused) 1=support_xyz 2=features 3=neighbor_idx
    // 4=W1 5=b1 6=W2 7=b2. Output: fp32 [B][C_OUT][M].
    const float* xyz  = (const float*)d_in[1];
    const float* feat = (const float*)d_in[2];
    const int*   nbr  = (const int*)d_in[3];
    const float* W1   = (const float*)d_in[4];
    const float* b1   = (const float*)d_in[5];
    const float* W2   = (const float*)d_in[6];
    const float* b2   = (const float*)d_in[7];
    float* out = (float*)d_out;
    (void)d_ws; (void)ws_size;

    prep_weights<<<176, 256, 0, stream>>>(W1, W2);
    conv_fused<<<dim3(N_ / 64, B_), 256, 0, stream>>>(feat, xyz, b1, b2);
    gather_max<<<32 * QB_, 256, 0, stream>>>(nbr, out);   // 6016 blocks
}

// Round 2
// 255.836 us; speedup vs baseline: 1.0463x; 1.0046x over previous
//
#include <hip/hip_runtime.h>

typedef unsigned short u16;
typedef short s16x8 __attribute__((ext_vector_type(8)));
typedef float f32x4 __attribute__((ext_vector_type(4)));
typedef unsigned short u16x8 __attribute__((ext_vector_type(8)));

#define B_   8
#define N_   24000
#define M_   6000
#define K_   32
#define CIN  64
#define CMID 128
#define COUT 256
#define KP1  96    // 67 zero-padded to 3x32 for MFMA K-steps
#define QB_  188   // ceil(M/32) query-blocks per (batch, quarter) combo

// Static device globals — no ws_size assumption, graph-capture safe,
// fully rewritten on every call. Weights in MFMA fragment order.
__device__ __align__(16) u16 g_W1f[CMID * KP1];                 // 24.6 KB bf16
__device__ __align__(16) u16 g_W2f[COUT * CMID];                // 65.5 KB bf16
__device__ __align__(16) u16 g_Yf[(size_t)B_ * N_ * COUT];      // 98.3 MB bf16

__device__ __forceinline__ float bf2f(u16 u) {
    return __uint_as_float(((unsigned)u) << 16);
}
__device__ __forceinline__ u16 f2bf(float f) {  // fp32 -> bf16 RNE
    unsigned u = __float_as_uint(f);
    u += 0x7FFFu + ((u >> 16) & 1u);
    return (u16)(u >> 16);
}

// ---------------------------------------------------------------------------
// Kernel 0: convert fp32 weights to bf16 in fragment order. (unchanged)
// ---------------------------------------------------------------------------
__global__ void prep_weights(const float* __restrict__ W1,
                             const float* __restrict__ W2) {
    int t = blockIdx.x * 256 + threadIdx.x;   // 0..45055
    if (t < CMID * KP1) {                     // 12288 -> W1f
        int blk = t >> 9, off = t & 511;
        int L = off >> 3, j = off & 7;
        int ln = L & 15, quad = L >> 4;
        int w = blk / 6, r = blk % 6;
        int k0i = r >> 1, mt = r & 1;
        int row = w * 32 + mt * 16 + ln;
        int col = k0i * 32 + quad * 8 + j;
        g_W1f[t] = (col < 67) ? f2bf(W1[row * 67 + col]) : (u16)0;
    } else {                                  // 32768 -> W2f
        int i = t - CMID * KP1;
        int blk = i >> 9, off = i & 511;
        int L = off >> 3, j = off & 7;
        int ln = L & 15, quad = L >> 4;
        int w = blk >> 4, r = blk & 15;
        int k0i = r >> 2, mt = r & 3;
        int row = w * 64 + mt * 16 + ln;
        int col = k0i * 32 + quad * 8 + j;
        g_W2f[i] = f2bf(W2[row * 128 + col]);
    }
}

// ---------------------------------------------------------------------------
// Kernel 1: fused conv1+relu+conv2+relu (BYTE-IDENTICAL to R7 — once gather
// drops below it, its counters surface in the top-5 for a theory-led edit).
// ---------------------------------------------------------------------------
__global__ __launch_bounds__(256) void conv_fused(
        const float* __restrict__ feat, const float* __restrict__ xyz,
        const float* __restrict__ b1,  const float* __restrict__ b2) {
    __shared__ __align__(16) u16 sm[16896];
    u16* Xs = sm;
    u16* Hs = sm + 6656;
    u16* Ys = sm;

    const int tid  = threadIdx.x;
    const int b    = blockIdx.y;
    const int n0   = blockIdx.x * 64;
    const int w    = tid >> 6;
    const int L    = tid & 63;
    const int ln   = L & 15;
    const int quad = L >> 4;

    if (tid < 64) {
        uint4 z; z.x = z.y = z.z = z.w = 0u;
        u16* xr = Xs + tid * 104;
        *(uint4*)(xr + 64) = z; *(uint4*)(xr + 72) = z;
        *(uint4*)(xr + 80) = z; *(uint4*)(xr + 88) = z;
        const float* s = xyz + (size_t)(b * N_ + n0 + tid) * 3;
        xr[64] = f2bf(s[0]); xr[65] = f2bf(s[1]); xr[66] = f2bf(s[2]);
    }
#pragma unroll
    for (int it = 0; it < 4; ++it) {
        int idx = it * 256 + tid;
        int c   = idx >> 4;
        int p0  = (idx & 15) << 2;
        float4 v = *(const float4*)(feat + (size_t)(b * CIN + c) * N_ + n0 + p0);
        u16* dst = Xs + p0 * 104 + c;
        dst[0]   = f2bf(v.x);
        dst[104] = f2bf(v.y);
        dst[208] = f2bf(v.z);
        dst[312] = f2bf(v.w);
    }
    __syncthreads();

    f32x4 acc1[2][4];
#pragma unroll
    for (int mt = 0; mt < 2; ++mt)
#pragma unroll
        for (int nt = 0; nt < 4; ++nt) {
            f32x4 zz = {0.f, 0.f, 0.f, 0.f};
            acc1[mt][nt] = zz;
        }
#pragma unroll
    for (int k0i = 0; k0i < 3; ++k0i) {
        s16x8 af[2], xf[4];
#pragma unroll
        for (int mt = 0; mt < 2; ++mt)
            af[mt] = *(const s16x8*)(g_W1f + (((w * 3 + k0i) * 2 + mt) << 9) + L * 8);
#pragma unroll
        for (int nt = 0; nt < 4; ++nt)
            xf[nt] = *(const s16x8*)(Xs + (nt * 16 + ln) * 104 + k0i * 32 + quad * 8);
#pragma unroll
        for (int mt = 0; mt < 2; ++mt)
#pragma unroll
            for (int nt = 0; nt < 4; ++nt)
                acc1[mt][nt] = __builtin_amdgcn_mfma_f32_16x16x32_bf16(
                    af[mt], xf[nt], acc1[mt][nt], 0, 0, 0);
    }
#pragma unroll
    for (int mt = 0; mt < 2; ++mt) {
        int m0 = w * 32 + mt * 16 + quad * 4;
        float4 bv = *(const float4*)(b1 + m0);
#pragma unroll
        for (int nt = 0; nt < 4; ++nt) {
            int p = nt * 16 + ln;
            float x0 = acc1[mt][nt][0] + bv.x;
            float x1 = acc1[mt][nt][1] + bv.y;
            float x2 = acc1[mt][nt][2] + bv.z;
            float x3 = acc1[mt][nt][3] + bv.w;
            ushort4 hv;
            hv.x = f2bf(x0 > 0.f ? x0 : 0.f);
            hv.y = f2bf(x1 > 0.f ? x1 : 0.f);
            hv.z = f2bf(x2 > 0.f ? x2 : 0.f);
            hv.w = f2bf(x3 > 0.f ? x3 : 0.f);
            *(ushort4*)(Hs + p * 136 + m0) = hv;
        }
    }
    __syncthreads();

    f32x4 acc2[4][4];
#pragma unroll
    for (int mt = 0; mt < 4; ++mt)
#pragma unroll
        for (int nt = 0; nt < 4; ++nt) {
            f32x4 zz = {0.f, 0.f, 0.f, 0.f};
            acc2[mt][nt] = zz;
        }
#pragma unroll
    for (int k0i = 0; k0i < 4; ++k0i) {
        s16x8 af[4], hf[4];
#pragma unroll
        for (int mt = 0; mt < 4; ++mt)
            af[mt] = *(const s16x8*)(g_W2f + (((w * 4 + k0i) * 4 + mt) << 9) + L * 8);
#pragma unroll
        for (int nt = 0; nt < 4; ++nt)
            hf[nt] = *(const s16x8*)(Hs + (nt * 16 + ln) * 136 + k0i * 32 + quad * 8);
#pragma unroll
        for (int mt = 0; mt < 4; ++mt)
#pragma unroll
            for (int nt = 0; nt < 4; ++nt)
                acc2[mt][nt] = __builtin_amdgcn_mfma_f32_16x16x32_bf16(
                    af[mt], hf[nt], acc2[mt][nt], 0, 0, 0);
    }
    __syncthreads();

#pragma unroll
    for (int mt = 0; mt < 4; ++mt) {
        int c0 = w * 64 + mt * 16 + quad * 4;
        float4 bv = *(const float4*)(b2 + c0);
#pragma unroll
        for (int nt = 0; nt < 4; ++nt) {
            int p = nt * 16 + ln;
            float x0 = acc2[mt][nt][0] + bv.x;
            float x1 = acc2[mt][nt][1] + bv.y;
            float x2 = acc2[mt][nt][2] + bv.z;
            float x3 = acc2[mt][nt][3] + bv.w;
            ushort4 yv;
            yv.x = f2bf(x0 > 0.f ? x0 : 0.f);
            yv.y = f2bf(x1 > 0.f ? x1 : 0.f);
            yv.z = f2bf(x2 > 0.f ? x2 : 0.f);
            yv.w = f2bf(x3 > 0.f ? x3 : 0.f);
            *(ushort4*)(Ys + p * 264 + c0) = yv;
        }
    }
    __syncthreads();

    u16* dstY = g_Yf + ((size_t)b * N_ + n0) * COUT;
#pragma unroll
    for (int i = 0; i < 8; ++i) {
        int g = i * 256 + tid;
        int p = g >> 5, c16 = g & 31;
        *(uint4*)(dstY + (size_t)p * COUT + c16 * 8) =
            *(const uint4*)(Ys + p * 264 + c16 * 8);
    }
}

// ---------------------------------------------------------------------------
// Kernel 2: gather + max, 3-phase BUCKET-SORTED version.
// R9 post-mortem of masked 2-phase (R8.5): FETCH 376->277 MB but VALUBusy
// 17->42% (mask/zero-select VALU duplicated per phase ate the win); dur only
// -6 us. Fix both: counting-sort each row's 32 indices by phase (p = idx>>13,
// 3 phases, slab ~1.05 MB) via LDS-atomic histogram+placement (~50 wave
// instrs), then each phase sweeps ONLY its own bucket:
//  - each index loaded exactly once total -> mask VALU gone;
//  - tail lanes clamp pos to end-1 (a DUPLICATE index of the SAME query row:
//    max(a,a)=a, so duplicates are free correctness-wise) -> no cndmask, no
//    divergence; wave-uniform rare loop covers buckets >16 (~2%);
//  - 3 x 1.05 MB phase-slabs: drift window ~2-3 MB <= 4 MB XCD-L2 ALWAYS;
//  - sort area (7.2 KB) aliases ymax (barrier-separated) -> LDS 29.7->25.6 KB
//    -> 6 blocks/CU; MLP=4 via row-quad batched loads (as R8 baseline).
// Predicted: FETCH 277->~160 MB, VALUBusy 42->~28%, dur 111->~85 us.
// Max in u16 domain (post-ReLU bf16, sign=0) = exact bf16 max.
// ---------------------------------------------------------------------------
__global__ __launch_bounds__(256) void gather_max(
        const int* __restrict__ nbr, float* __restrict__ out) {
    __shared__ __align__(16) u16 smem[32 * 400];          // 25.6 KB union
    int* sidx  = (int*)smem;                              // [1024] bytes 0..4095
    u16* ssort = smem + 2048;                             // [1024] bytes 4096..6143
    int* soff  = (int*)(smem + 3072);                     // [128]  bytes 6144..6655
    int* scur  = (int*)(smem + 3328);                     // [128]  bytes 6656..7167
    u16* ymax  = smem;                                    // [32*400] post-gather

    const int tid = threadIdx.x;
    const int l   = blockIdx.x;
    const int xcd = l & 7;
    const int j   = l >> 3;          // 0..751
    const int cw  = j / QB_;         // combo-within-XCD 0..3
    const int qb  = j % QB_;         // query-block 0..187
    const int combo = cw * 8 + xcd;  // 0..31
    const int b   = combo >> 2;
    const int q   = combo & 3;       // channel quarter (64 ch)
    const int m0  = qb * 32;
    const int row = tid >> 3;        // row owning this thread's 4 staged ints
    const int Mv0 = M_ - m0;
    const int Mv  = Mv0 < 32 ? Mv0 : 32;   // valid rows this block (16 or 32)

    // stage neighbor indices (32 queries x 32 k) + zero bucket counters
    if (row < Mv)
        *(int4*)(sidx + tid * 4) =
            *(const int4*)(nbr + ((size_t)b * M_ + m0) * K_ + tid * 4);
    if (tid < 128) scur[tid] = 0;
    __syncthreads();

    // pass 1: per-row phase histogram (phases 0,1 only; 2 is implied)
    unsigned uu[4];
#pragma unroll
    for (int jj = 0; jj < 4; ++jj) {
        unsigned u = (unsigned)sidx[tid * 4 + jj];
        u = u < (unsigned)N_ ? u : 0u;     // defensive clamp (also garbage rows)
        uu[jj] = u;
        int p = (int)(u >> 13);            // 0:[0,8192) 1:[8192,16384) 2:rest
        if (p < 2) atomicAdd(&scur[row * 4 + p], 1);
    }
    __syncthreads();

    // prefix: bucket offsets; reset cursors to bucket starts
    if (tid < 32) {
        int c0 = scur[tid * 4 + 0], c1 = scur[tid * 4 + 1];
        soff[tid * 4 + 0] = 0;
        soff[tid * 4 + 1] = c0;
        soff[tid * 4 + 2] = c0 + c1;
        soff[tid * 4 + 3] = 32;
        scur[tid * 4 + 0] = 0;
        scur[tid * 4 + 1] = c0;
        scur[tid * 4 + 2] = c0 + c1;
    }
    __syncthreads();

    // pass 2: place indices into phase buckets (order within bucket arbitrary)
#pragma unroll
    for (int jj = 0; jj < 4; ++jj) {
        int p = (int)(uu[jj] >> 13);
        int pos = atomicAdd(&scur[row * 4 + p], 1);
        ssort[row * 32 + pos] = (u16)uu[jj];
    }
    __syncthreads();

    const int w  = tid >> 6;         // wave 0..3
    const int L  = tid & 63;
    const int kg = L >> 3;           // k-slot within bucket round
    const int co = L & 7;            // channel octet within quarter
    const u16* base = g_Yf + (size_t)b * N_ * COUT + q * 64 + co * 8;

    u16x8 mx[8];
#pragma unroll
    for (int i = 0; i < 8; ++i)
        mx[i] = (u16x8){0, 0, 0, 0, 0, 0, 0, 0};

#pragma unroll
    for (int p = 0; p < 3; ++p) {
#pragma unroll
        for (int h = 0; h < 2; ++h) {          // two row-quads per wave
            int mq[4], beg[4], end[4], last[4];
            u16x8 va[4], vb[4];
            // round 0: 4 independent loads (MLP=4)
#pragma unroll
            for (int s = 0; s < 4; ++s) {
                int ml = w * 8 + h * 4 + s;
                mq[s]  = ml < Mv ? ml : 0;     // dead rows redirect to row 0
                beg[s] = soff[mq[s] * 4 + p];
                end[s] = soff[mq[s] * 4 + p + 1];
                int lt = end[s] - 1;
                last[s] = lt > 0 ? lt : 0;
                int p0 = beg[s] + kg; p0 = p0 < last[s] ? p0 : last[s];
                unsigned i0 = (unsigned)ssort[mq[s] * 32 + p0];
                va[s] = *(const u16x8*)(base + (size_t)i0 * COUT);
            }
            // round 1 (duplicate-clamped when bucket <= 8)
#pragma unroll
            for (int s = 0; s < 4; ++s) {
                int p1 = beg[s] + 8 + kg; p1 = p1 < last[s] ? p1 : last[s];
                unsigned i1 = (unsigned)ssort[mq[s] * 32 + p1];
                vb[s] = *(const u16x8*)(base + (size_t)i1 * COUT);
            }
#pragma unroll
            for (int s = 0; s < 4; ++s)
                mx[h * 4 + s] = __builtin_elementwise_max(mx[h * 4 + s],
                    __builtin_elementwise_max(va[s], vb[s]));
            // rare tail: bucket > 16 (~2% of row-phases), wave-uniform trip
#pragma unroll
            for (int s = 0; s < 4; ++s) {
                for (int r = beg[s] + 16; r < end[s]; r += 8) {
                    int pp = r + kg; pp = pp < last[s] ? pp : last[s];
                    unsigned ii = (unsigned)ssort[mq[s] * 32 + pp];
                    u16x8 vv = *(const u16x8*)(base + (size_t)ii * COUT);
                    mx[h * 4 + s] = __builtin_elementwise_max(mx[h * 4 + s], vv);
                }
            }
        }
    }

    __syncthreads();   // all ssort/soff reads done; ymax aliases that storage

    // reduce across the 8 k-slots (lane bits 3,4,5)
#pragma unroll
    for (int i = 0; i < 8; ++i) {
        int ml = w * 8 + i;
        if (ml < Mv) {
            u16x8 m8 = mx[i];
#pragma unroll
            for (int mask = 8; mask <= 32; mask <<= 1) {
                int4 t = *(int4*)&m8;
                t.x = __shfl_xor(t.x, mask);
                t.y = __shfl_xor(t.y, mask);
                t.z = __shfl_xor(t.z, mask);
                t.w = __shfl_xor(t.w, mask);
                m8 = __builtin_elementwise_max(m8, *(u16x8*)&t);
            }
            if (kg == 0)   // one replicate writes 8 channels, 16B ds_write
                *(u16x8*)(ymax + ml * 400 + co * 8) = m8;
        }
    }
    __syncthreads();

    // transpose + bf16->fp32: out[b][q*64+c][m0..m0+31]
    int valid = Mv;
#pragma unroll
    for (int it = 0; it < 2; ++it) {
        int c  = it * 32 + (tid >> 3);   // local channel 0..63
        int mc = (tid & 7) << 2;
        if (mc + 4 <= valid) {
            float4 v;
            v.x = bf2f(ymax[(mc + 0) * 400 + c]);
            v.y = bf2f(ymax[(mc + 1) * 400 + c]);
            v.z = bf2f(ymax[(mc + 2) * 400 + c]);
            v.w = bf2f(ymax[(mc + 3) * 400 + c]);
            *(float4*)(out + (size_t)(b * COUT + q * 64 + c) * M_ + m0 + mc) = v;
        }
    }
}

extern "C" void kernel_launch(void* const* d_in, const int* in_sizes, int n_in,
                              void* d_out, int out_size, void* d_ws, size_t ws_size,
                              hipStream_t stream) {
    // inputs (all fp32 except neighbor_idx int32):
    // 0=query_xyz(unused) 1=support_xyz 2=features 3=neighbor_idx
    // 4=W1 5=b1 6=W2 7=b2. Output: fp32 [B][C_OUT][M].
    const float* xyz  = (const float*)d_in[1];
    const float* feat = (const float*)d_in[2];
    const int*   nbr  = (const int*)d_in[3];
    const float* W1   = (const float*)d_in[4];
    const float* b1   = (const float*)d_in[5];
    const float* W2   = (const float*)d_in[6];
    const float* b2   = (const float*)d_in[7];
    float* out = (float*)d_out;
    (void)d_ws; (void)ws_size;

    prep_weights<<<176, 256, 0, stream>>>(W1, W2);
    conv_fused<<<dim3(N_ / 64, B_), 256, 0, stream>>>(feat, xyz, b1, b2);
    gather_max<<<32 * QB_, 256, 0, stream>>>(nbr, out);   // 6016 blocks
}